// Round 2
// baseline (572.306 us; speedup 1.0000x reference)
//
#include <hip/hip_runtime.h>

#define L_CHUNK 128
#define BATCH   8
#define NHEADS  16
#define DKDIM   64
#define DMODEL  1024   // NHEADS*DKDIM
#define T0CACHE 4096
#define TTOT    4224
#define ROWSTR  8192   // BATCH*NHEADS*DKDIM

// float4 elements per K or V cache tensor (4096*8192 floats / 4)
#define N8PER   8388608u
// copy split points: kernel1 [0,SPLIT1), kernel2 [SPLIT1,SPLIT2), kernel3 [SPLIT2,N8PER)
// chosen so every copy block does exactly 8 iterations
#define SPLIT1  5242880u
#define SPLIT2  6815744u

typedef __attribute__((ext_vector_type(8))) __bf16 bf16x8;
typedef __attribute__((ext_vector_type(4))) float f32x4;
typedef __attribute__((ext_vector_type(8))) unsigned short us8;

__device__ __forceinline__ unsigned short f2bf(float f) {
    unsigned int u = __float_as_uint(f);
    u += 0x7fffu + ((u >> 16) & 1u);   // round-to-nearest-even
    return (unsigned short)(u >> 16);
}

// grid-stride copy of [e0,e1) float4 range of BOTH K and V caches
__device__ __forceinline__ void copy_slice(int cid, int ncopy,
        unsigned e0, unsigned e1,
        float4* __restrict__ Kd, const float4* __restrict__ Kc,
        float4* __restrict__ Vd, const float4* __restrict__ Vc) {
    const unsigned stride = (unsigned)ncopy * 256u;
    const unsigned base = e0 + (unsigned)cid * 256u + threadIdx.x;
    for (unsigned e = base; e < e1; e += stride) Kd[e] = Kc[e];
    for (unsigned e = base; e < e1; e += stride) Vd[e] = Vc[e];
}

// ---------------- GEMM body: C = A(MxK) * B(KxN) + bias ----------------
// AF32/BF32: operand is fp32 in memory, converted to bf16 on the fly during staging.
// MODE 0: fp32 C -> Cf[row*N+col].  MODE 1: qkv split: q->bf16 Cq, K/V->fp32 C1/C2.
template<int MODE, bool AF32, bool BF32>
__device__ __forceinline__ void gemm_body(
        int bx, int by,
        const void* __restrict__ Ap,
        const void* __restrict__ Bp,
        const float* __restrict__ bias,
        float* __restrict__ Cf, unsigned short* __restrict__ Cq,
        float* __restrict__ C1, float* __restrict__ C2,
        int K, int N) {
    __shared__ unsigned short Al[64][40];
    __shared__ unsigned short Bl[64][40];

    const int tid  = threadIdx.x;
    const int wave = tid >> 6;
    const int lane = tid & 63;
    const int m0 = by * 64;
    const int n0 = bx * 64;

    f32x4 zero = {0.f, 0.f, 0.f, 0.f};
    f32x4 acc[4];
    #pragma unroll
    for (int i = 0; i < 4; ++i) acc[i] = zero;

    const int ar = tid >> 2, ac = (tid & 3) * 8;
    const int bk = tid >> 3, bn = (tid & 7) * 8;
    const int rot = tid & 7;
    const int mrow = wave * 16 + (lane & 15);
    const int koff = (lane >> 4) * 8;

    for (int k0 = 0; k0 < K; k0 += 32) {
        us8 av, bv;
        if constexpr (AF32) {
            const float* A = (const float*)Ap;
            const float4 a0 = *(const float4*)(A + (size_t)(m0 + ar) * K + (k0 + ac));
            const float4 a1 = *(const float4*)(A + (size_t)(m0 + ar) * K + (k0 + ac) + 4);
            av[0] = f2bf(a0.x); av[1] = f2bf(a0.y); av[2] = f2bf(a0.z); av[3] = f2bf(a0.w);
            av[4] = f2bf(a1.x); av[5] = f2bf(a1.y); av[6] = f2bf(a1.z); av[7] = f2bf(a1.w);
        } else {
            const unsigned short* A = (const unsigned short*)Ap;
            av = *(const us8*)(A + (size_t)(m0 + ar) * K + (k0 + ac));
        }
        if constexpr (BF32) {
            const float* B = (const float*)Bp;
            const float4 b0 = *(const float4*)(B + (size_t)(k0 + bk) * N + (n0 + bn));
            const float4 b1 = *(const float4*)(B + (size_t)(k0 + bk) * N + (n0 + bn) + 4);
            bv[0] = f2bf(b0.x); bv[1] = f2bf(b0.y); bv[2] = f2bf(b0.z); bv[3] = f2bf(b0.w);
            bv[4] = f2bf(b1.x); bv[5] = f2bf(b1.y); bv[6] = f2bf(b1.z); bv[7] = f2bf(b1.w);
        } else {
            const unsigned short* B = (const unsigned short*)Bp;
            bv = *(const us8*)(B + (size_t)(k0 + bk) * N + (n0 + bn));
        }
        *(us8*)(&Al[ar][ac]) = av;
        #pragma unroll
        for (int i = 0; i < 8; ++i) {
            int ii = (i + rot) & 7;
            Bl[bn + ii][bk] = bv[ii];
        }
        __syncthreads();
        bf16x8 af = __builtin_bit_cast(bf16x8, *(const us8*)(&Al[mrow][koff]));
        #pragma unroll
        for (int nt = 0; nt < 4; ++nt) {
            bf16x8 bf = __builtin_bit_cast(bf16x8,
                            *(const us8*)(&Bl[nt * 16 + (lane & 15)][koff]));
            acc[nt] = __builtin_amdgcn_mfma_f32_16x16x32_bf16(af, bf, acc[nt], 0, 0, 0);
        }
        __syncthreads();
    }

    const int colt  = lane & 15;
    const int rbase = (lane >> 4) * 4;
    #pragma unroll
    for (int nt = 0; nt < 4; ++nt) {
        int gcol = n0 + nt * 16 + colt;
        float bval = bias[gcol];
        #pragma unroll
        for (int r = 0; r < 4; ++r) {
            int grow = m0 + wave * 16 + rbase + r;
            float val = acc[nt][r] + bval;
            if (MODE == 0) {
                Cf[(size_t)grow * N + gcol] = val;
            } else {
                int s = gcol >> 10, w = gcol & 1023;
                int l = grow >> 3, b = grow & 7;
                size_t kvoff = (size_t)(T0CACHE + l) * ROWSTR + (size_t)b * DMODEL + w;
                if (s == 0)      Cq[(size_t)grow * DMODEL + w] = f2bf(val);
                else if (s == 1) C1[kvoff] = val;
                else             C2[kvoff] = val;
            }
        }
    }
}

// ---------------- kernel 1: qkv GEMM (768 blocks) + 62.5% of cache copy ----------------
__global__ __launch_bounds__(256) void qkv_and_copy(
        const float* __restrict__ x,
        const float* __restrict__ qkv_w,
        const float* __restrict__ qkv_b,
        unsigned short* __restrict__ qb,
        float* __restrict__ Kout, float* __restrict__ Vout,
        const float4* __restrict__ Kc, const float4* __restrict__ Vc) {
    const int g = blockIdx.x;
    const bool isGemm = (g < 3072) && ((g & 3) == 0);
    if (isGemm) {
        int gi = g >> 2;                 // 0..767
        gemm_body<1, true, true>(gi % 48, gi / 48, x, qkv_w, qkv_b,
                                 nullptr, qb, Kout, Vout, DMODEL, 3 * DMODEL);
    } else {
        int cid = (g < 3072) ? (g - (g >> 2) - 1) : (g - 768);   // 0..2559
        copy_slice(cid, 2560, 0u, SPLIT1, (float4*)Kout, Kc, (float4*)Vout, Vc);
    }
}

// ---------------- kernel 2: MFMA flash attention (256 blocks) + 18.75% copy ----------------
__global__ __launch_bounds__(256) void attn_mfma(
        const unsigned short* __restrict__ qb,
        const float* __restrict__ Kout,
        const float* __restrict__ Vout,
        unsigned short* __restrict__ ob,
        const float4* __restrict__ Kc, const float4* __restrict__ Vc) {
    __shared__ unsigned short Kb[128][72];       // [key][d], pad 72
    __shared__ unsigned short Vt[64][136];       // [d][key], pad 136
    __shared__ unsigned short Pb[4][16][136];    // per wave [row][key]

    if (blockIdx.x >= 256) {                     // copy blocks
        copy_slice(blockIdx.x - 256, 768, SPLIT1, SPLIT2,
                   (float4*)Kout, Kc, (float4*)Vout, Vc);
        return;
    }

    const int tid  = threadIdx.x;
    const int wave = tid >> 6, lane = tid & 63;
    const int qh = blockIdx.x & 1, bh = blockIdx.x >> 1;
    const int b = bh >> 4, h = bh & 15;
    const int q0 = qh * 64;
    const size_t base = (size_t)T0CACHE * ROWSTR + (size_t)b * DMODEL + h * DKDIM;

    // stage K row-major + V transposed, fp32 -> bf16 (always full 128 keys)
    for (int e = tid; e < 2048; e += 256) {      // 128 rows x 16 float4
        int j = e >> 4, d4 = (e & 15) * 4;
        float4 kv = *(const float4*)(Kout + base + (size_t)j * ROWSTR + d4);
        ushort4 u; u.x = f2bf(kv.x); u.y = f2bf(kv.y); u.z = f2bf(kv.z); u.w = f2bf(kv.w);
        *(ushort4*)&Kb[j][d4] = u;
        float4 vv = *(const float4*)(Vout + base + (size_t)j * ROWSTR + d4);
        Vt[d4 + 0][j] = f2bf(vv.x); Vt[d4 + 1][j] = f2bf(vv.y);
        Vt[d4 + 2][j] = f2bf(vv.z); Vt[d4 + 3][j] = f2bf(vv.w);
    }

    // Q fragments (A-layout: m=lane&15, k=(lane>>4)*8+j), 2 k-steps of 32
    const int qrow = q0 + wave * 16 + (lane & 15);
    const size_t arow = (size_t)(qrow * 8 + b) * DMODEL + h * DKDIM;
    bf16x8 qa0 = __builtin_bit_cast(bf16x8, *(const us8*)(qb + arow + (lane >> 4) * 8));
    bf16x8 qa1 = __builtin_bit_cast(bf16x8, *(const us8*)(qb + arow + 32 + (lane >> 4) * 8));
    __syncthreads();

    // S = Q K^T : 8 key-tiles of 16
    f32x4 sacc[8];
    f32x4 zero = {0.f, 0.f, 0.f, 0.f};
    #pragma unroll
    for (int t = 0; t < 8; ++t) sacc[t] = zero;
    #pragma unroll
    for (int t = 0; t < 8; ++t) {
        bf16x8 k0 = __builtin_bit_cast(bf16x8,
                        *(const us8*)(&Kb[t * 16 + (lane & 15)][(lane >> 4) * 8]));
        bf16x8 k1 = __builtin_bit_cast(bf16x8,
                        *(const us8*)(&Kb[t * 16 + (lane & 15)][32 + (lane >> 4) * 8]));
        sacc[t] = __builtin_amdgcn_mfma_f32_16x16x32_bf16(qa0, k0, sacc[t], 0, 0, 0);
        sacc[t] = __builtin_amdgcn_mfma_f32_16x16x32_bf16(qa1, k1, sacc[t], 0, 0, 0);
    }

    // mask + row softmax. C-layout: col=lane&15, row=(lane>>4)*4+reg.
    const int col = lane & 15;
    float mrow[4], lsum[4], inv[4];
    #pragma unroll
    for (int r = 0; r < 4; ++r) mrow[r] = -3e38f;
    #pragma unroll
    for (int t = 0; t < 8; ++t) {
        #pragma unroll
        for (int r = 0; r < 4; ++r) {
            int key = t * 16 + col;
            int qi  = q0 + wave * 16 + (lane >> 4) * 4 + r;
            float v = sacc[t][r] * 0.125f;
            if (key > qi) v = -1e9f;
            sacc[t][r] = v;
            mrow[r] = fmaxf(mrow[r], v);
        }
    }
    #pragma unroll
    for (int r = 0; r < 4; ++r) {
        #pragma unroll
        for (int off = 1; off < 16; off <<= 1)
            mrow[r] = fmaxf(mrow[r], __shfl_xor(mrow[r], off, 64));
        lsum[r] = 0.f;
    }
    #pragma unroll
    for (int t = 0; t < 8; ++t) {
        #pragma unroll
        for (int r = 0; r < 4; ++r) {
            float p = __expf(sacc[t][r] - mrow[r]);
            lsum[r] += p;
            Pb[wave][(lane >> 4) * 4 + r][t * 16 + col] = f2bf(p);
        }
    }
    #pragma unroll
    for (int r = 0; r < 4; ++r) {
        #pragma unroll
        for (int off = 1; off < 16; off <<= 1)
            lsum[r] += __shfl_xor(lsum[r], off, 64);
        inv[r] = 1.f / lsum[r];
    }
    __syncthreads();

    // O = P V : P in A-layout from LDS, V^T gives B-layout b128 reads
    bf16x8 pa[4];
    #pragma unroll
    for (int ks = 0; ks < 4; ++ks)
        pa[ks] = __builtin_bit_cast(bf16x8,
                     *(const us8*)(&Pb[wave][lane & 15][ks * 32 + (lane >> 4) * 8]));
    f32x4 oacc[4];
    #pragma unroll
    for (int n = 0; n < 4; ++n) oacc[n] = zero;
    #pragma unroll
    for (int n = 0; n < 4; ++n) {
        #pragma unroll
        for (int ks = 0; ks < 4; ++ks) {
            bf16x8 vb = __builtin_bit_cast(bf16x8,
                            *(const us8*)(&Vt[n * 16 + (lane & 15)][ks * 32 + (lane >> 4) * 8]));
            oacc[n] = __builtin_amdgcn_mfma_f32_16x16x32_bf16(pa[ks], vb, oacc[n], 0, 0, 0);
        }
    }

    // store O (bf16) to ob rows (l*8+b), cols h*64 + d
    #pragma unroll
    for (int n = 0; n < 4; ++n) {
        #pragma unroll
        for (int r = 0; r < 4; ++r) {
            int qi = q0 + wave * 16 + (lane >> 4) * 4 + r;
            int d  = n * 16 + col;
            ob[(size_t)(qi * 8 + b) * DMODEL + h * DKDIM + d] = f2bf(oacc[n][r] * inv[r]);
        }
    }
}

// ---------------- kernel 3: out GEMM (256 blocks) + 18.75% copy ----------------
__global__ __launch_bounds__(256) void out_gemm(
        const unsigned short* __restrict__ ob,
        const float* __restrict__ out_w,
        const float* __restrict__ out_b, float* __restrict__ y,
        float* __restrict__ Kout, float* __restrict__ Vout,
        const float4* __restrict__ Kc, const float4* __restrict__ Vc) {
    const int g = blockIdx.x;
    if (g >= 256) {
        copy_slice(g - 256, 768, SPLIT2, N8PER,
                   (float4*)Kout, Kc, (float4*)Vout, Vc);
        return;
    }
    gemm_body<0, false, true>(g & 15, g >> 4, ob, out_w, out_b,
                              y, nullptr, nullptr, nullptr, DMODEL, DMODEL);
}

extern "C" void kernel_launch(void* const* d_in, const int* in_sizes, int n_in,
                              void* d_out, int out_size, void* d_ws, size_t ws_size,
                              hipStream_t stream) {
    const float* x     = (const float*)d_in[0];
    const float* Kc    = (const float*)d_in[1];
    const float* Vc    = (const float*)d_in[2];
    const float* qkv_w = (const float*)d_in[3];
    const float* qkv_b = (const float*)d_in[4];
    const float* out_w = (const float*)d_in[5];
    const float* out_b = (const float*)d_in[6];

    float* y    = (float*)d_out;
    float* Kout = y + (size_t)L_CHUNK * BATCH * DMODEL;
    float* Vout = Kout + (size_t)TTOT * ROWSTR;

    char* ws = (char*)d_ws;
    unsigned short* qb = (unsigned short*)ws;                        // 2 MB bf16 q
    unsigned short* ob = (unsigned short*)(ws + (size_t)(2 << 20));  // 2 MB bf16 attn out

    qkv_and_copy<<<3328, 256, 0, stream>>>(x, qkv_w, qkv_b, qb, Kout, Vout,
                                           (const float4*)Kc, (const float4*)Vc);

    attn_mfma<<<1024, 256, 0, stream>>>(qb, Kout, Vout, ob,
                                        (const float4*)Kc, (const float4*)Vc);

    out_gemm<<<1024, 256, 0, stream>>>(ob, out_w, out_b, y, Kout, Vout,
                                       (const float4*)Kc, (const float4*)Vc);
}

// Round 3
// 542.503 us; speedup vs baseline: 1.0549x; 1.0549x over previous
//
#include <hip/hip_runtime.h>

#define L_CHUNK 128
#define BATCH   8
#define NHEADS  16
#define DKDIM   64
#define DMODEL  1024   // NHEADS*DKDIM
#define T0CACHE 4096
#define TTOT    4224
#define ROWSTR  8192   // BATCH*NHEADS*DKDIM

// float4 elements per K or V cache tensor (4096*8192 floats / 4)
#define N8PER   8388608u
// copy split: attn kernel [0,CSPLIT), out kernel [CSPLIT,N8PER); 2048 copy blocks
// each => exactly 8 grid-stride iterations per block per tensor
#define CSPLIT  4194304u

typedef __attribute__((ext_vector_type(8))) __bf16 bf16x8;
typedef __attribute__((ext_vector_type(4))) float f32x4;
typedef __attribute__((ext_vector_type(8))) unsigned short us8;

__device__ __forceinline__ unsigned short f2bf(float f) {
    unsigned int u = __float_as_uint(f);
    u += 0x7fffu + ((u >> 16) & 1u);   // round-to-nearest-even
    return (unsigned short)(u >> 16);
}

// grid-stride copy of [e0,e1) float4 range of BOTH K and V caches
__device__ __forceinline__ void copy_slice(int cid, int ncopy,
        unsigned e0, unsigned e1,
        float4* __restrict__ Kd, const float4* __restrict__ Kc,
        float4* __restrict__ Vd, const float4* __restrict__ Vc) {
    const unsigned stride = (unsigned)ncopy * 256u;
    const unsigned base = e0 + (unsigned)cid * 256u + threadIdx.x;
    #pragma unroll 4
    for (unsigned e = base; e < e1; e += stride) Kd[e] = Kc[e];
    #pragma unroll 4
    for (unsigned e = base; e < e1; e += stride) Vd[e] = Vc[e];
}

// ---------------- GEMM body: C = A(MxK) * B(KxN) + bias ----------------
// 2-phase software pipeline: issue tile t+1 global loads into registers BEFORE
// computing tile t from LDS, so load latency hides under MFMA + barrier.
// AF32/BF32: operand is fp32 in memory, converted to bf16 at the LDS-write stage
// (conversion is off the load critical path).
// MODE 0: fp32 C -> Cf[row*N+col].  MODE 1: qkv split: q->bf16 Cq, K/V->fp32 C1/C2.
template<int MODE, bool AF32, bool BF32>
__device__ __forceinline__ void gemm_body(
        int bx, int by,
        const void* __restrict__ Ap,
        const void* __restrict__ Bp,
        const float* __restrict__ bias,
        float* __restrict__ Cf, unsigned short* __restrict__ Cq,
        float* __restrict__ C1, float* __restrict__ C2,
        int K, int N) {
    __shared__ unsigned short Al[64][40];
    __shared__ unsigned short Bl[64][40];

    const int tid  = threadIdx.x;
    const int wave = tid >> 6;
    const int lane = tid & 63;
    const int m0 = by * 64;
    const int n0 = bx * 64;

    f32x4 zero = {0.f, 0.f, 0.f, 0.f};
    f32x4 acc[4];
    #pragma unroll
    for (int i = 0; i < 4; ++i) acc[i] = zero;

    const int ar = tid >> 2, ac = (tid & 3) * 8;
    const int bk = tid >> 3, bn = (tid & 7) * 8;
    const int rot = tid & 7;
    const int mrow = wave * 16 + (lane & 15);
    const int koff = (lane >> 4) * 8;

    float4 a0, a1, b0, b1;     // staged fp32 regs (AF32/BF32 path)
    us8 a16, b16;              // staged bf16 regs (pre-converted path)

    auto LOAD = [&](int k0) {
        if constexpr (AF32) {
            const float* A = (const float*)Ap;
            a0 = *(const float4*)(A + (size_t)(m0 + ar) * K + (k0 + ac));
            a1 = *(const float4*)(A + (size_t)(m0 + ar) * K + (k0 + ac) + 4);
        } else {
            a16 = *(const us8*)((const unsigned short*)Ap + (size_t)(m0 + ar) * K + (k0 + ac));
        }
        if constexpr (BF32) {
            const float* B = (const float*)Bp;
            b0 = *(const float4*)(B + (size_t)(k0 + bk) * N + (n0 + bn));
            b1 = *(const float4*)(B + (size_t)(k0 + bk) * N + (n0 + bn) + 4);
        } else {
            b16 = *(const us8*)((const unsigned short*)Bp + (size_t)(k0 + bk) * N + (n0 + bn));
        }
    };
    auto STORE = [&]() {
        us8 av, bv;
        if constexpr (AF32) {
            av[0] = f2bf(a0.x); av[1] = f2bf(a0.y); av[2] = f2bf(a0.z); av[3] = f2bf(a0.w);
            av[4] = f2bf(a1.x); av[5] = f2bf(a1.y); av[6] = f2bf(a1.z); av[7] = f2bf(a1.w);
        } else av = a16;
        if constexpr (BF32) {
            bv[0] = f2bf(b0.x); bv[1] = f2bf(b0.y); bv[2] = f2bf(b0.z); bv[3] = f2bf(b0.w);
            bv[4] = f2bf(b1.x); bv[5] = f2bf(b1.y); bv[6] = f2bf(b1.z); bv[7] = f2bf(b1.w);
        } else bv = b16;
        *(us8*)(&Al[ar][ac]) = av;
        #pragma unroll
        for (int i = 0; i < 8; ++i) {
            int ii = (i + rot) & 7;
            Bl[bn + ii][bk] = bv[ii];
        }
    };
    auto COMPUTE = [&]() {
        bf16x8 af = __builtin_bit_cast(bf16x8, *(const us8*)(&Al[mrow][koff]));
        #pragma unroll
        for (int nt = 0; nt < 4; ++nt) {
            bf16x8 bf = __builtin_bit_cast(bf16x8,
                            *(const us8*)(&Bl[nt * 16 + (lane & 15)][koff]));
            acc[nt] = __builtin_amdgcn_mfma_f32_16x16x32_bf16(af, bf, acc[nt], 0, 0, 0);
        }
    };

    // prologue: stage tile 0
    LOAD(0);
    STORE();
    __syncthreads();
    for (int k0 = 32; k0 < K; k0 += 32) {
        LOAD(k0);          // tile t+1 loads in flight during compute + barrier
        COMPUTE();         // tile t from LDS
        __syncthreads();   // all waves done reading LDS
        STORE();           // waitcnt on loads happens here, off the long path
        __syncthreads();   // LDS ready
    }
    COMPUTE();             // last tile

    const int colt  = lane & 15;
    const int rbase = (lane >> 4) * 4;
    #pragma unroll
    for (int nt = 0; nt < 4; ++nt) {
        int gcol = n0 + nt * 16 + colt;
        float bval = bias[gcol];
        #pragma unroll
        for (int r = 0; r < 4; ++r) {
            int grow = m0 + wave * 16 + rbase + r;
            float val = acc[nt][r] + bval;
            if (MODE == 0) {
                Cf[(size_t)grow * N + gcol] = val;
            } else {
                int s = gcol >> 10, w = gcol & 1023;
                int l = grow >> 3, b = grow & 7;
                size_t kvoff = (size_t)(T0CACHE + l) * ROWSTR + (size_t)b * DMODEL + w;
                if (s == 0)      Cq[(size_t)grow * DMODEL + w] = f2bf(val);
                else if (s == 1) C1[kvoff] = val;
                else             C2[kvoff] = val;
            }
        }
    }
}

// ---------------- kernel 1: pure qkv GEMM (768 blocks, no copy competition) ----------------
__global__ __launch_bounds__(256) void qkv_gemm(
        const float* __restrict__ x,
        const float* __restrict__ qkv_w,
        const float* __restrict__ qkv_b,
        unsigned short* __restrict__ qb,
        float* __restrict__ Kout, float* __restrict__ Vout) {
    int gi = blockIdx.x;                 // 0..767
    gemm_body<1, true, true>(gi % 48, gi / 48, x, qkv_w, qkv_b,
                             nullptr, qb, Kout, Vout, DMODEL, 3 * DMODEL);
}

// ---------------- kernel 2: MFMA flash attention (256 blocks) + 50% copy ----------------
__global__ __launch_bounds__(256) void attn_mfma(
        const unsigned short* __restrict__ qb,
        const float* __restrict__ Kout,
        const float* __restrict__ Vout,
        unsigned short* __restrict__ ob,
        const float4* __restrict__ Kc, const float4* __restrict__ Vc) {
    __shared__ unsigned short Kb[128][72];       // [key][d], pad 72
    __shared__ unsigned short Vt[64][136];       // [d][key], pad 136
    __shared__ unsigned short Pb[4][16][136];    // per wave [row][key]

    if (blockIdx.x >= 256) {                     // copy blocks
        copy_slice(blockIdx.x - 256, 2048, 0u, CSPLIT,
                   (float4*)Kout, Kc, (float4*)Vout, Vc);
        return;
    }

    const int tid  = threadIdx.x;
    const int wave = tid >> 6, lane = tid & 63;
    const int qh = blockIdx.x & 1, bh = blockIdx.x >> 1;
    const int b = bh >> 4, h = bh & 15;
    const int q0 = qh * 64;
    const size_t base = (size_t)T0CACHE * ROWSTR + (size_t)b * DMODEL + h * DKDIM;

    // stage K row-major + V transposed, fp32 -> bf16 (always full 128 keys)
    for (int e = tid; e < 2048; e += 256) {      // 128 rows x 16 float4
        int j = e >> 4, d4 = (e & 15) * 4;
        float4 kv = *(const float4*)(Kout + base + (size_t)j * ROWSTR + d4);
        ushort4 u; u.x = f2bf(kv.x); u.y = f2bf(kv.y); u.z = f2bf(kv.z); u.w = f2bf(kv.w);
        *(ushort4*)&Kb[j][d4] = u;
        float4 vv = *(const float4*)(Vout + base + (size_t)j * ROWSTR + d4);
        Vt[d4 + 0][j] = f2bf(vv.x); Vt[d4 + 1][j] = f2bf(vv.y);
        Vt[d4 + 2][j] = f2bf(vv.z); Vt[d4 + 3][j] = f2bf(vv.w);
    }

    // Q fragments (A-layout: m=lane&15, k=(lane>>4)*8+j), 2 k-steps of 32
    const int qrow = q0 + wave * 16 + (lane & 15);
    const size_t arow = (size_t)(qrow * 8 + b) * DMODEL + h * DKDIM;
    bf16x8 qa0 = __builtin_bit_cast(bf16x8, *(const us8*)(qb + arow + (lane >> 4) * 8));
    bf16x8 qa1 = __builtin_bit_cast(bf16x8, *(const us8*)(qb + arow + 32 + (lane >> 4) * 8));
    __syncthreads();

    // S = Q K^T : 8 key-tiles of 16
    f32x4 sacc[8];
    f32x4 zero = {0.f, 0.f, 0.f, 0.f};
    #pragma unroll
    for (int t = 0; t < 8; ++t) sacc[t] = zero;
    #pragma unroll
    for (int t = 0; t < 8; ++t) {
        bf16x8 k0 = __builtin_bit_cast(bf16x8,
                        *(const us8*)(&Kb[t * 16 + (lane & 15)][(lane >> 4) * 8]));
        bf16x8 k1 = __builtin_bit_cast(bf16x8,
                        *(const us8*)(&Kb[t * 16 + (lane & 15)][32 + (lane >> 4) * 8]));
        sacc[t] = __builtin_amdgcn_mfma_f32_16x16x32_bf16(qa0, k0, sacc[t], 0, 0, 0);
        sacc[t] = __builtin_amdgcn_mfma_f32_16x16x32_bf16(qa1, k1, sacc[t], 0, 0, 0);
    }

    // mask + row softmax. C-layout: col=lane&15, row=(lane>>4)*4+reg.
    const int col = lane & 15;
    float mrow[4], lsum[4], inv[4];
    #pragma unroll
    for (int r = 0; r < 4; ++r) mrow[r] = -3e38f;
    #pragma unroll
    for (int t = 0; t < 8; ++t) {
        #pragma unroll
        for (int r = 0; r < 4; ++r) {
            int key = t * 16 + col;
            int qi  = q0 + wave * 16 + (lane >> 4) * 4 + r;
            float v = sacc[t][r] * 0.125f;
            if (key > qi) v = -1e9f;
            sacc[t][r] = v;
            mrow[r] = fmaxf(mrow[r], v);
        }
    }
    #pragma unroll
    for (int r = 0; r < 4; ++r) {
        #pragma unroll
        for (int off = 1; off < 16; off <<= 1)
            mrow[r] = fmaxf(mrow[r], __shfl_xor(mrow[r], off, 64));
        lsum[r] = 0.f;
    }
    #pragma unroll
    for (int t = 0; t < 8; ++t) {
        #pragma unroll
        for (int r = 0; r < 4; ++r) {
            float p = __expf(sacc[t][r] - mrow[r]);
            lsum[r] += p;
            Pb[wave][(lane >> 4) * 4 + r][t * 16 + col] = f2bf(p);
        }
    }
    #pragma unroll
    for (int r = 0; r < 4; ++r) {
        #pragma unroll
        for (int off = 1; off < 16; off <<= 1)
            lsum[r] += __shfl_xor(lsum[r], off, 64);
        inv[r] = 1.f / lsum[r];
    }
    __syncthreads();

    // O = P V : P in A-layout from LDS, V^T gives B-layout b128 reads
    bf16x8 pa[4];
    #pragma unroll
    for (int ks = 0; ks < 4; ++ks)
        pa[ks] = __builtin_bit_cast(bf16x8,
                     *(const us8*)(&Pb[wave][lane & 15][ks * 32 + (lane >> 4) * 8]));
    f32x4 oacc[4];
    #pragma unroll
    for (int n = 0; n < 4; ++n) oacc[n] = zero;
    #pragma unroll
    for (int n = 0; n < 4; ++n) {
        #pragma unroll
        for (int ks = 0; ks < 4; ++ks) {
            bf16x8 vb = __builtin_bit_cast(bf16x8,
                            *(const us8*)(&Vt[n * 16 + (lane & 15)][ks * 32 + (lane >> 4) * 8]));
            oacc[n] = __builtin_amdgcn_mfma_f32_16x16x32_bf16(pa[ks], vb, oacc[n], 0, 0, 0);
        }
    }

    // store O (bf16) to ob rows (l*8+b), cols h*64 + d
    #pragma unroll
    for (int n = 0; n < 4; ++n) {
        #pragma unroll
        for (int r = 0; r < 4; ++r) {
            int qi = q0 + wave * 16 + (lane >> 4) * 4 + r;
            int d  = n * 16 + col;
            ob[(size_t)(qi * 8 + b) * DMODEL + h * DKDIM + d] = f2bf(oacc[n][r] * inv[r]);
        }
    }
}

// ---------------- kernel 3: out GEMM (256 blocks) + 50% copy ----------------
__global__ __launch_bounds__(256) void out_gemm(
        const unsigned short* __restrict__ ob,
        const float* __restrict__ out_w,
        const float* __restrict__ out_b, float* __restrict__ y,
        float* __restrict__ Kout, float* __restrict__ Vout,
        const float4* __restrict__ Kc, const float4* __restrict__ Vc) {
    const int g = blockIdx.x;
    if (g >= 256) {
        copy_slice(g - 256, 2048, CSPLIT, N8PER,
                   (float4*)Kout, Kc, (float4*)Vout, Vc);
        return;
    }
    gemm_body<0, false, true>(g & 15, g >> 4, ob, out_w, out_b,
                              y, nullptr, nullptr, nullptr, DMODEL, DMODEL);
}

extern "C" void kernel_launch(void* const* d_in, const int* in_sizes, int n_in,
                              void* d_out, int out_size, void* d_ws, size_t ws_size,
                              hipStream_t stream) {
    const float* x     = (const float*)d_in[0];
    const float* Kc    = (const float*)d_in[1];
    const float* Vc    = (const float*)d_in[2];
    const float* qkv_w = (const float*)d_in[3];
    const float* qkv_b = (const float*)d_in[4];
    const float* out_w = (const float*)d_in[5];
    const float* out_b = (const float*)d_in[6];

    float* y    = (float*)d_out;
    float* Kout = y + (size_t)L_CHUNK * BATCH * DMODEL;
    float* Vout = Kout + (size_t)TTOT * ROWSTR;

    char* ws = (char*)d_ws;
    unsigned short* qb = (unsigned short*)ws;                        // 2 MB bf16 q
    unsigned short* ob = (unsigned short*)(ws + (size_t)(2 << 20));  // 2 MB bf16 attn out

    qkv_gemm<<<768, 256, 0, stream>>>(x, qkv_w, qkv_b, qb, Kout, Vout);

    attn_mfma<<<2304, 256, 0, stream>>>(qb, Kout, Vout, ob,
                                        (const float4*)Kc, (const float4*)Vc);

    out_gemm<<<2304, 256, 0, stream>>>(ob, out_w, out_b, y, Kout, Vout,
                                       (const float4*)Kc, (const float4*)Vc);
}

// Round 5
// 531.773 us; speedup vs baseline: 1.0762x; 1.0202x over previous
//
#include <hip/hip_runtime.h>

#define L_CHUNK 128
#define BATCH   8
#define NHEADS  16
#define DKDIM   64
#define DMODEL  1024   // NHEADS*DKDIM
#define T0CACHE 4096
#define TTOT    4224
#define ROWSTR  8192   // BATCH*NHEADS*DKDIM

// float4 elements per K or V cache tensor (4096*8192 floats / 4)
#define N8PER   8388608u
// copy split: 2048 copy blocks, stride 524288 float4 per pass.
// prep: 7 passes, attn: 5, out: 4  (7+5+4 = 16 passes exactly covers N8PER)
#define SPLITA  3670016u
#define SPLITB  6291456u

typedef __attribute__((ext_vector_type(8))) __bf16 bf16x8;
typedef __attribute__((ext_vector_type(4))) float f32x4;
typedef __attribute__((ext_vector_type(8))) unsigned short us8;

__device__ __forceinline__ unsigned short f2bf(float f) {
    unsigned int u = __float_as_uint(f);
    u += 0x7fffu + ((u >> 16) & 1u);   // round-to-nearest-even
    return (unsigned short)(u >> 16);
}

// grid-stride copy of [e0,e1) float4 range of BOTH K and V caches
__device__ __forceinline__ void copy_slice(int cid, int ncopy,
        unsigned e0, unsigned e1,
        float4* __restrict__ Kd, const float4* __restrict__ Kc,
        float4* __restrict__ Vd, const float4* __restrict__ Vc) {
    const unsigned stride = (unsigned)ncopy * 256u;
    const unsigned base = e0 + (unsigned)cid * 256u + threadIdx.x;
    for (unsigned e = base; e < e1; e += stride) Kd[e] = Kc[e];
    for (unsigned e = base; e < e1; e += stride) Vd[e] = Vc[e];
}

// ---------------- GEMM body: C = A(MxK bf16) * B(KxN bf16) + bias ----------------
// 2-phase software pipeline: issue tile t+1 global loads into registers BEFORE
// computing tile t from LDS, so load latency hides under MFMA + barrier.
// MODE 0: fp32 C -> Cf[row*N+col].  MODE 1: qkv split: q->bf16 Cq, K/V->fp32 C1/C2.
template<int MODE>
__device__ __forceinline__ void gemm_body(
        int bx, int by,
        const unsigned short* __restrict__ A,
        const unsigned short* __restrict__ B,
        const float* __restrict__ bias,
        float* __restrict__ Cf, unsigned short* __restrict__ Cq,
        float* __restrict__ C1, float* __restrict__ C2,
        int K, int N) {
    __shared__ unsigned short Al[64][40];
    __shared__ unsigned short Bl[64][40];

    const int tid  = threadIdx.x;
    const int wave = tid >> 6;
    const int lane = tid & 63;
    const int m0 = by * 64;
    const int n0 = bx * 64;

    f32x4 zero = {0.f, 0.f, 0.f, 0.f};
    f32x4 acc[4];
    #pragma unroll
    for (int i = 0; i < 4; ++i) acc[i] = zero;

    const int ar = tid >> 2, ac = (tid & 3) * 8;
    const int bk = tid >> 3, bn = (tid & 7) * 8;
    const int rot = tid & 7;
    const int mrow = wave * 16 + (lane & 15);
    const int koff = (lane >> 4) * 8;

    us8 a16, b16;      // staged regs for next tile

    auto LOAD = [&](int k0) {
        a16 = *(const us8*)(A + (size_t)(m0 + ar) * K + (k0 + ac));
        b16 = *(const us8*)(B + (size_t)(k0 + bk) * N + (n0 + bn));
    };
    auto STORE = [&]() {
        *(us8*)(&Al[ar][ac]) = a16;
        #pragma unroll
        for (int i = 0; i < 8; ++i) {
            int ii = (i + rot) & 7;
            Bl[bn + ii][bk] = b16[ii];
        }
    };
    auto COMPUTE = [&]() {
        bf16x8 af = __builtin_bit_cast(bf16x8, *(const us8*)(&Al[mrow][koff]));
        #pragma unroll
        for (int nt = 0; nt < 4; ++nt) {
            bf16x8 bf = __builtin_bit_cast(bf16x8,
                            *(const us8*)(&Bl[nt * 16 + (lane & 15)][koff]));
            acc[nt] = __builtin_amdgcn_mfma_f32_16x16x32_bf16(af, bf, acc[nt], 0, 0, 0);
        }
    };

    // prologue: stage tile 0
    LOAD(0);
    STORE();
    __syncthreads();
    for (int k0 = 32; k0 < K; k0 += 32) {
        LOAD(k0);          // tile t+1 loads in flight during compute + barrier
        COMPUTE();         // tile t from LDS
        __syncthreads();   // all waves done reading LDS
        STORE();           // waitcnt for staged loads lands here
        __syncthreads();   // LDS ready
    }
    COMPUTE();             // last tile

    const int colt  = lane & 15;
    const int rbase = (lane >> 4) * 4;
    #pragma unroll
    for (int nt = 0; nt < 4; ++nt) {
        int gcol = n0 + nt * 16 + colt;
        float bval = bias[gcol];
        #pragma unroll
        for (int r = 0; r < 4; ++r) {
            int grow = m0 + wave * 16 + rbase + r;
            float val = acc[nt][r] + bval;
            if (MODE == 0) {
                Cf[(size_t)grow * N + gcol] = val;
            } else {
                int s = gcol >> 10, w = gcol & 1023;
                int l = grow >> 3, b = grow & 7;
                size_t kvoff = (size_t)(T0CACHE + l) * ROWSTR + (size_t)b * DMODEL + w;
                if (s == 0)      Cq[(size_t)grow * DMODEL + w] = f2bf(val);
                else if (s == 1) C1[kvoff] = val;
                else             C2[kvoff] = val;
            }
        }
    }
}

// ---------------- kernel 0: fp32->bf16 convert (512 blocks) + 7/16 copy (2048 blocks) ----------------
__global__ __launch_bounds__(256) void prep_and_copy(
        const float* __restrict__ x, const float* __restrict__ qkv_w,
        const float* __restrict__ out_w,
        unsigned short* __restrict__ xb, unsigned short* __restrict__ wb,
        unsigned short* __restrict__ owb,
        float* __restrict__ Kout, float* __restrict__ Vout,
        const float4* __restrict__ Kc, const float4* __restrict__ Vc) {
    const int g = blockIdx.x;
    if (g < 512) {
        // grid-stride over 1,310,720 float4 (x: 262144, qkv_w: 786432, out_w: 262144)
        for (int idx = g * 256 + threadIdx.x; idx < 1310720; idx += 512 * 256) {
            const float4* s4; ushort4* d4; int rel;
            if (idx < 262144)        { s4 = (const float4*)x;     d4 = (ushort4*)xb;  rel = idx; }
            else if (idx < 1048576)  { s4 = (const float4*)qkv_w; d4 = (ushort4*)wb;  rel = idx - 262144; }
            else                     { s4 = (const float4*)out_w; d4 = (ushort4*)owb; rel = idx - 1048576; }
            float4 v = s4[rel];
            ushort4 o; o.x = f2bf(v.x); o.y = f2bf(v.y); o.z = f2bf(v.z); o.w = f2bf(v.w);
            d4[rel] = o;
        }
    } else {
        copy_slice(g - 512, 2048, 0u, SPLITA, (float4*)Kout, Kc, (float4*)Vout, Vc);
    }
}

// ---------------- kernel 1: pure qkv GEMM, bf16 operands (768 blocks) ----------------
__global__ __launch_bounds__(256) void qkv_gemm(
        const unsigned short* __restrict__ xb,
        const unsigned short* __restrict__ wb,
        const float* __restrict__ qkv_b,
        unsigned short* __restrict__ qb,
        float* __restrict__ Kout, float* __restrict__ Vout) {
    int gi = blockIdx.x;                 // 0..767
    gemm_body<1>(gi % 48, gi / 48, xb, wb, qkv_b,
                 nullptr, qb, Kout, Vout, DMODEL, 3 * DMODEL);
}

// ---------------- kernel 2: MFMA flash attention (256 blocks) + 5/16 copy (2048 blocks) ----
// LDS: P-buffer aliases the K-buffer (K dead after QK^T) -> 35 KB total, 4 blocks/CU.
__global__ __launch_bounds__(256) void attn_mfma(
        const unsigned short* __restrict__ qb,
        const float* __restrict__ Kout,
        const float* __restrict__ Vout,
        unsigned short* __restrict__ ob,
        const float4* __restrict__ Kc, const float4* __restrict__ Vc) {
    __shared__ unsigned short KPb[128][72];      // K [key][d] pad 72; later P per-wave
    __shared__ unsigned short Vt[64][136];       // V^T [d][key], pad 136

    if (blockIdx.x >= 256) {                     // copy blocks
        copy_slice(blockIdx.x - 256, 2048, SPLITA, SPLITB,
                   (float4*)Kout, Kc, (float4*)Vout, Vc);
        return;
    }

    const int tid  = threadIdx.x;
    const int wave = tid >> 6, lane = tid & 63;
    const int qh = blockIdx.x & 1, bh = blockIdx.x >> 1;
    const int b = bh >> 4, h = bh & 15;
    const int q0 = qh * 64;
    const size_t base = (size_t)T0CACHE * ROWSTR + (size_t)b * DMODEL + h * DKDIM;

    // stage K row-major + V transposed, fp32 -> bf16 (always full 128 keys)
    for (int e = tid; e < 2048; e += 256) {      // 128 rows x 16 float4
        int j = e >> 4, d4 = (e & 15) * 4;
        float4 kv = *(const float4*)(Kout + base + (size_t)j * ROWSTR + d4);
        ushort4 u; u.x = f2bf(kv.x); u.y = f2bf(kv.y); u.z = f2bf(kv.z); u.w = f2bf(kv.w);
        *(ushort4*)&KPb[j][d4] = u;
        float4 vv = *(const float4*)(Vout + base + (size_t)j * ROWSTR + d4);
        Vt[d4 + 0][j] = f2bf(vv.x); Vt[d4 + 1][j] = f2bf(vv.y);
        Vt[d4 + 2][j] = f2bf(vv.z); Vt[d4 + 3][j] = f2bf(vv.w);
    }

    // Q fragments (A-layout: m=lane&15, k=(lane>>4)*8+j), 2 k-steps of 32
    const int qrow = q0 + wave * 16 + (lane & 15);
    const size_t arow = (size_t)(qrow * 8 + b) * DMODEL + h * DKDIM;
    bf16x8 qa0 = __builtin_bit_cast(bf16x8, *(const us8*)(qb + arow + (lane >> 4) * 8));
    bf16x8 qa1 = __builtin_bit_cast(bf16x8, *(const us8*)(qb + arow + 32 + (lane >> 4) * 8));
    __syncthreads();

    // S = Q K^T : 8 key-tiles of 16
    f32x4 sacc[8];
    f32x4 zero = {0.f, 0.f, 0.f, 0.f};
    #pragma unroll
    for (int t = 0; t < 8; ++t) sacc[t] = zero;
    #pragma unroll
    for (int t = 0; t < 8; ++t) {
        bf16x8 k0 = __builtin_bit_cast(bf16x8,
                        *(const us8*)(&KPb[t * 16 + (lane & 15)][(lane >> 4) * 8]));
        bf16x8 k1 = __builtin_bit_cast(bf16x8,
                        *(const us8*)(&KPb[t * 16 + (lane & 15)][32 + (lane >> 4) * 8]));
        sacc[t] = __builtin_amdgcn_mfma_f32_16x16x32_bf16(qa0, k0, sacc[t], 0, 0, 0);
        sacc[t] = __builtin_amdgcn_mfma_f32_16x16x32_bf16(qa1, k1, sacc[t], 0, 0, 0);
    }
    __syncthreads();   // all waves done reading K; its LDS may now hold P

    // per-wave P region aliased onto KPb: 16 rows x 136 keys
    unsigned short* Pw = &KPb[0][0] + wave * 16 * 136;

    // mask + row softmax. C-layout: col=lane&15, row=(lane>>4)*4+reg.
    const int col = lane & 15;
    float mrow[4], lsum[4], inv[4];
    #pragma unroll
    for (int r = 0; r < 4; ++r) mrow[r] = -3e38f;
    #pragma unroll
    for (int t = 0; t < 8; ++t) {
        #pragma unroll
        for (int r = 0; r < 4; ++r) {
            int key = t * 16 + col;
            int qi  = q0 + wave * 16 + (lane >> 4) * 4 + r;
            float v = sacc[t][r] * 0.125f;
            if (key > qi) v = -1e9f;
            sacc[t][r] = v;
            mrow[r] = fmaxf(mrow[r], v);
        }
    }
    #pragma unroll
    for (int r = 0; r < 4; ++r) {
        #pragma unroll
        for (int off = 1; off < 16; off <<= 1)
            mrow[r] = fmaxf(mrow[r], __shfl_xor(mrow[r], off, 64));
        lsum[r] = 0.f;
    }
    #pragma unroll
    for (int t = 0; t < 8; ++t) {
        #pragma unroll
        for (int r = 0; r < 4; ++r) {
            float p = __expf(sacc[t][r] - mrow[r]);
            lsum[r] += p;
            Pw[((lane >> 4) * 4 + r) * 136 + t * 16 + col] = f2bf(p);
        }
    }
    #pragma unroll
    for (int r = 0; r < 4; ++r) {
        #pragma unroll
        for (int off = 1; off < 16; off <<= 1)
            lsum[r] += __shfl_xor(lsum[r], off, 64);
        inv[r] = 1.f / lsum[r];
    }

    // O = P V : P in A-layout from LDS (per-wave region), V^T gives B-layout b128 reads
    bf16x8 pa[4];
    #pragma unroll
    for (int ks = 0; ks < 4; ++ks)
        pa[ks] = __builtin_bit_cast(bf16x8,
                     *(const us8*)(Pw + (lane & 15) * 136 + ks * 32 + (lane >> 4) * 8));
    f32x4 oacc[4];
    #pragma unroll
    for (int n = 0; n < 4; ++n) oacc[n] = zero;
    #pragma unroll
    for (int n = 0; n < 4; ++n) {
        #pragma unroll
        for (int ks = 0; ks < 4; ++ks) {
            bf16x8 vb = __builtin_bit_cast(bf16x8,
                            *(const us8*)(&Vt[n * 16 + (lane & 15)][ks * 32 + (lane >> 4) * 8]));
            oacc[n] = __builtin_amdgcn_mfma_f32_16x16x32_bf16(pa[ks], vb, oacc[n], 0, 0, 0);
        }
    }

    // store O (bf16) to ob rows (l*8+b), cols h*64 + d
    #pragma unroll
    for (int n = 0; n < 4; ++n) {
        #pragma unroll
        for (int r = 0; r < 4; ++r) {
            int qi = q0 + wave * 16 + (lane >> 4) * 4 + r;
            int d  = n * 16 + col;
            ob[(size_t)(qi * 8 + b) * DMODEL + h * DKDIM + d] = f2bf(oacc[n][r] * inv[r]);
        }
    }
}

// ---------------- kernel 3: out GEMM bf16 (256 blocks) + 4/16 copy (2048 blocks) ----------------
__global__ __launch_bounds__(256) void out_gemm(
        const unsigned short* __restrict__ ob,
        const unsigned short* __restrict__ owb,
        const float* __restrict__ out_b, float* __restrict__ y,
        float* __restrict__ Kout, float* __restrict__ Vout,
        const float4* __restrict__ Kc, const float4* __restrict__ Vc) {
    const int g = blockIdx.x;
    if (g >= 256) {
        copy_slice(g - 256, 2048, SPLITB, N8PER,
                   (float4*)Kout, Kc, (float4*)Vout, Vc);
        return;
    }
    gemm_body<0>(g & 15, g >> 4, ob, owb, out_b,
                 y, nullptr, nullptr, nullptr, DMODEL, DMODEL);
}

extern "C" void kernel_launch(void* const* d_in, const int* in_sizes, int n_in,
                              void* d_out, int out_size, void* d_ws, size_t ws_size,
                              hipStream_t stream) {
    const float* x     = (const float*)d_in[0];
    const float* Kc    = (const float*)d_in[1];
    const float* Vc    = (const float*)d_in[2];
    const float* qkv_w = (const float*)d_in[3];
    const float* qkv_b = (const float*)d_in[4];
    const float* out_w = (const float*)d_in[5];
    const float* out_b = (const float*)d_in[6];

    float* y    = (float*)d_out;
    float* Kout = y + (size_t)L_CHUNK * BATCH * DMODEL;
    float* Vout = Kout + (size_t)TTOT * ROWSTR;

    char* ws = (char*)d_ws;
    unsigned short* xb  = (unsigned short*)ws;                        // 2 MB
    unsigned short* wb  = (unsigned short*)(ws + (size_t)(2  << 20)); // 6 MB
    unsigned short* owb = (unsigned short*)(ws + (size_t)(8  << 20)); // 2 MB
    unsigned short* qb  = (unsigned short*)(ws + (size_t)(10 << 20)); // 2 MB (bf16 q)
    unsigned short* ob  = (unsigned short*)(ws + (size_t)(12 << 20)); // 2 MB

    prep_and_copy<<<2560, 256, 0, stream>>>(x, qkv_w, out_w, xb, wb, owb,
                                            Kout, Vout,
                                            (const float4*)Kc, (const float4*)Vc);

    qkv_gemm<<<768, 256, 0, stream>>>(xb, wb, qkv_b, qb, Kout, Vout);

    attn_mfma<<<2304, 256, 0, stream>>>(qb, Kout, Vout, ob,
                                        (const float4*)Kc, (const float4*)Vc);

    out_gemm<<<2304, 256, 0, stream>>>(ob, owb, out_b, y, Kout, Vout,
                                       (const float4*)Kc, (const float4*)Vc);
}